// Round 1
// baseline (2926.003 us; speedup 1.0000x reference)
//
#include <hip/hip_runtime.h>
#include <hip/hip_bf16.h>
#include <stdint.h>

// Problem constants (exact divisibility everywhere; B=65536)
#define BATCH   65536
#define INDIM   512
#define HDIM    512
#define H3      1536
#define NHEAD   8
#define HEADD   64

typedef __attribute__((ext_vector_type(4))) float  f32x4;
typedef __attribute__((ext_vector_type(8))) __bf16 bf16x8;
typedef __attribute__((ext_vector_type(4))) __bf16 bf16x4;

// async global->LDS, 16B per lane. LDS dest must be contiguous in lane order.
__device__ __forceinline__ void gl_lds16(const void* g, void* l) {
  __builtin_amdgcn_global_load_lds(
      (const __attribute__((address_space(1))) unsigned int*)g,
      (__attribute__((address_space(3))) unsigned int*)l, 16, 0, 0);
}

// ---------------- prep: f32 -> bf16 (weights) ----------------
__global__ void convert_kernel(const float* __restrict__ s, __bf16* __restrict__ d, int n4) {
  int i = blockIdx.x * blockDim.x + threadIdx.x;
  int stride = gridDim.x * blockDim.x;
  for (; i < n4; i += stride) {
    float4 v = ((const float4*)s)[i];
    bf16x4 o = {(__bf16)v.x, (__bf16)v.y, (__bf16)v.z, (__bf16)v.w};
    ((bf16x4*)d)[i] = o;
  }
}

// ---------------- GEMM1: h_pre[m,n] = sum_k x[m,k]*W_fc[n,k] + b_fc[n] ----------------
// 128x128 tile, BK=32, 256 threads (4 waves, 2x2 wave grid), mfma 16x16x32 bf16.
__global__ __launch_bounds__(256) void gemm1_kernel(
    const float* __restrict__ x, const __bf16* __restrict__ Wfc,
    const float* __restrict__ bfc, __bf16* __restrict__ hpre)
{
  __shared__ __align__(16) __bf16 sA[128 * 32];  // 8 KB
  __shared__ __align__(16) __bf16 sB[128 * 32];  // 8 KB
  const int tid  = threadIdx.x;
  const int wave = tid >> 6, lane = tid & 63;
  const int wm = wave >> 1, wn = wave & 1;
  const int lrow = lane & 15, quad = lane >> 4;
  const int m0 = blockIdx.y * 128, n0 = blockIdx.x * 128;

  f32x4 acc[4][4] = {};

  for (int k0 = 0; k0 < 512; k0 += 32) {
    __syncthreads();  // protect LDS from previous iter's fragment reads
    // A: x fp32 -> bf16 inline. 128 rows x 32 cols; 1024 float4 slots / 256 threads.
    {
      const float* xb = x + (size_t)m0 * 512 + k0;
      #pragma unroll
      for (int i = 0; i < 4; i++) {
        int slot = i * 256 + tid;
        int row = slot >> 3, c4 = (slot & 7) * 4;
        float4 v = *(const float4*)&xb[(size_t)row * 512 + c4];
        bf16x4 o = {(__bf16)v.x, (__bf16)v.y, (__bf16)v.z, (__bf16)v.w};
        *(bf16x4*)&sA[row * 32 + c4] = o;
      }
    }
    // B: W_fc bf16 rows n0..n0+127, async 16B/lane
    {
      const __bf16* Wb = Wfc + (size_t)n0 * 512 + k0;
      int row = tid >> 2, c8 = (tid & 3) * 8;
      gl_lds16(Wb + (size_t)row * 512 + c8,        &sB[row * 32 + c8]);
      gl_lds16(Wb + (size_t)(row + 64) * 512 + c8, &sB[(row + 64) * 32 + c8]);
    }
    __syncthreads();
    bf16x8 af[4], bfr[4];
    #pragma unroll
    for (int i = 0; i < 4; i++) af[i]  = *(bf16x8*)&sA[(wm * 64 + i * 16 + lrow) * 32 + quad * 8];
    #pragma unroll
    for (int j = 0; j < 4; j++) bfr[j] = *(bf16x8*)&sB[(wn * 64 + j * 16 + lrow) * 32 + quad * 8];
    #pragma unroll
    for (int i = 0; i < 4; i++)
      #pragma unroll
      for (int j = 0; j < 4; j++)
        acc[i][j] = __builtin_amdgcn_mfma_f32_16x16x32_bf16(af[i], bfr[j], acc[i][j], 0, 0, 0);
  }

  // epilogue: + b_fc, cast bf16, store h_pre [BATCH, 1536]
  #pragma unroll
  for (int i = 0; i < 4; i++) {
    int gm = m0 + wm * 64 + i * 16 + quad * 4;
    #pragma unroll
    for (int j = 0; j < 4; j++) {
      int gn = n0 + wn * 64 + j * 16 + lrow;
      float bv = bfc[gn];
      #pragma unroll
      for (int r = 0; r < 4; r++)
        hpre[(size_t)(gm + r) * H3 + gn] = (__bf16)(acc[i][j][r] + bv);
    }
  }
}

// ---------------- LayerNorm(1536) + ReLU, in place on h (bf16) ----------------
// one wave per batch row; 4 rows per 256-thread block
__global__ __launch_bounds__(256) void ln_relu_kernel(
    __bf16* __restrict__ h, const float* __restrict__ g, const float* __restrict__ bta)
{
  int row  = blockIdx.x * 4 + (threadIdx.x >> 6);
  int lane = threadIdx.x & 63;
  __bf16* hr = h + (size_t)row * H3;
  float v[24];
  float s1 = 0.f, s2 = 0.f;
  #pragma unroll
  for (int i = 0; i < 3; i++) {
    bf16x8 x8 = *(bf16x8*)&hr[i * 512 + lane * 8];
    #pragma unroll
    for (int j = 0; j < 8; j++) { float f = (float)x8[j]; v[i * 8 + j] = f; s1 += f; s2 += f * f; }
  }
  #pragma unroll
  for (int off = 32; off > 0; off >>= 1) { s1 += __shfl_down(s1, off, 64); s2 += __shfl_down(s2, off, 64); }
  s1 = __shfl(s1, 0, 64); s2 = __shfl(s2, 0, 64);
  float mu = s1 * (1.f / 1536.f);
  float rs = rsqrtf(s2 * (1.f / 1536.f) - mu * mu + 1e-5f);
  #pragma unroll
  for (int i = 0; i < 3; i++) {
    int c0 = i * 512 + lane * 8;
    bf16x8 o;
    #pragma unroll
    for (int j = 0; j < 8; j++) {
      float val = (v[i * 8 + j] - mu) * rs * g[c0 + j] + bta[c0 + j];
      o[j] = (__bf16)fmaxf(val, 0.f);
    }
    *(bf16x8*)&hr[c0] = o;
  }
}

// ---------------- fused tail: GEMM2 + attention + GEMM3 + gumbel-softmax ----------------
// block = 256 threads (4 waves) handles 16 batch rows = 48 token rows.
__global__ __launch_bounds__(256) void tail_kernel(
    const __bf16* __restrict__ h,      // [3B, 512] (= [B,1536])
    const __bf16* __restrict__ Wqkv,   // [1536, 512] bf16
    const float*  __restrict__ bqkv,   // [1536]
    const __bf16* __restrict__ Wo,     // [512, 512] bf16
    const float*  __restrict__ bo,     // [512]
    const float*  __restrict__ gum,    // [B, 3, 512]
    float* __restrict__ out)           // y0|y1|y2, each [B,512]
{
  __shared__ __align__(16) __bf16 sA[48 * 64];     // 6 KB: h chunk [48][64]
  __shared__ __align__(16) __bf16 sW[192 * 64];    // 24 KB: Wqkv chunk [192][64] / Wo chunk [128][64]
  __shared__ __align__(16) char   sPool[24576];    // sQKV [48][192] bf16 + sCtxH [48][64] bf16; reused as sOut [48][128] f32
  __shared__ float sAttn[16][12];

  __bf16* sQKV  = (__bf16*)sPool;            // 18432 B
  __bf16* sCtxH = (__bf16*)(sPool + 18432);  // 6144 B
  float*  sOut  = (float*)sPool;             // 24576 B

  const int tid  = threadIdx.x;
  const int wave = tid >> 6, lane = tid & 63;
  const int lrow = lane & 15, quad = lane >> 4;
  const int bi0 = blockIdx.x * 16;   // first batch row of tile
  const int R0  = blockIdx.x * 48;   // first token row of tile
  const int bi = tid >> 4, jt = tid & 15;  // attention-phase mapping

  f32x4 oacc[3][8] = {};   // attn_out accumulators [48 rows][512 cols] across block

  for (int hd = 0; hd < NHEAD; hd++) {
    // ---- GEMM2: qkv chunk [48 rows, 192 cols(q64|k64|v64)] , K=512, BK=64 ----
    f32x4 qacc[3][3] = {};
    for (int k0 = 0; k0 < 512; k0 += 64) {
      __syncthreads();
      {  // A: h rows R0..R0+47, cols k0..k0+63 : 384 slots of 16B
        int row = tid >> 3, c = tid & 7;
        gl_lds16(h + (size_t)(R0 + row) * 512 + k0 + c * 8, &sA[row * 64 + c * 8]);
        if (tid < 128) {
          int slot = 256 + tid;
          int row2 = slot >> 3, c2 = slot & 7;
          gl_lds16(h + (size_t)(R0 + row2) * 512 + k0 + c2 * 8, &sA[row2 * 64 + c2 * 8]);
        }
      }
      #pragma unroll
      for (int i = 0; i < 6; i++) {  // W: 192 rows x 128B = 1536 slots
        int slot = i * 256 + tid;
        int row = slot >> 3, c = slot & 7;
        int gq = (row < 64) ? (hd * 64 + row)
               : (row < 128) ? (512 + hd * 64 + (row - 64))
                             : (1024 + hd * 64 + (row - 128));
        gl_lds16(Wqkv + (size_t)gq * 512 + k0 + c * 8, &sW[row * 64 + c * 8]);
      }
      __syncthreads();
      #pragma unroll
      for (int kk = 0; kk < 2; kk++) {
        bf16x8 af[3], bfr[3];
        #pragma unroll
        for (int i = 0; i < 3; i++) af[i]  = *(bf16x8*)&sA[(i * 16 + lrow) * 64 + kk * 32 + quad * 8];
        #pragma unroll
        for (int j = 0; j < 3; j++) bfr[j] = *(bf16x8*)&sW[(wave * 48 + j * 16 + lrow) * 64 + kk * 32 + quad * 8];
        #pragma unroll
        for (int i = 0; i < 3; i++)
          #pragma unroll
          for (int j = 0; j < 3; j++)
            qacc[i][j] = __builtin_amdgcn_mfma_f32_16x16x32_bf16(af[i], bfr[j], qacc[i][j], 0, 0, 0);
      }
    }
    __syncthreads();
    // write qkv (+bias) to LDS
    #pragma unroll
    for (int i = 0; i < 3; i++)
      #pragma unroll
      for (int j = 0; j < 3; j++) {
        int col = wave * 48 + j * 16 + lrow;
        int gq = (col < 64) ? (hd * 64 + col)
               : (col < 128) ? (512 + hd * 64 + (col - 64))
                             : (1024 + hd * 64 + (col - 128));
        float bv = bqkv[gq];
        #pragma unroll
        for (int r = 0; r < 4; r++)
          sQKV[(i * 16 + quad * 4 + r) * 192 + col] = (__bf16)(qacc[i][j][r] + bv);
      }
    __syncthreads();

    // ---- attention (per batch row, 3x3, VALU) ----
    if (jt < 9) {
      int qt = jt / 3, kt = jt % 3;
      const __bf16* qv = &sQKV[(3 * bi + qt) * 192];
      const __bf16* kv = &sQKV[(3 * bi + kt) * 192 + 64];
      float s = 0.f;
      #pragma unroll
      for (int d8 = 0; d8 < 8; d8++) {
        bf16x8 q8 = *(bf16x8*)&qv[d8 * 8];
        bf16x8 k8 = *(bf16x8*)&kv[d8 * 8];
        #pragma unroll
        for (int u = 0; u < 8; u++) s += (float)q8[u] * (float)k8[u];
      }
      sAttn[bi][jt] = s * 0.125f;  // 1/sqrt(64)
    }
    __syncthreads();
    if (jt < 3) {
      float a0 = sAttn[bi][jt * 3], a1 = sAttn[bi][jt * 3 + 1], a2 = sAttn[bi][jt * 3 + 2];
      float mx = fmaxf(a0, fmaxf(a1, a2));
      float e0 = __expf(a0 - mx), e1 = __expf(a1 - mx), e2 = __expf(a2 - mx);
      float inv = 1.f / (e0 + e1 + e2);
      sAttn[bi][jt * 3] = e0 * inv; sAttn[bi][jt * 3 + 1] = e1 * inv; sAttn[bi][jt * 3 + 2] = e2 * inv;
    }
    __syncthreads();
    #pragma unroll
    for (int qt = 0; qt < 3; qt++) {
      float a0 = sAttn[bi][qt * 3], a1 = sAttn[bi][qt * 3 + 1], a2 = sAttn[bi][qt * 3 + 2];
      #pragma unroll
      for (int dd = 0; dd < 4; dd++) {
        int d = jt * 4 + dd;
        float vv = a0 * (float)sQKV[(3 * bi + 0) * 192 + 128 + d]
                 + a1 * (float)sQKV[(3 * bi + 1) * 192 + 128 + d]
                 + a2 * (float)sQKV[(3 * bi + 2) * 192 + 128 + d];
        sCtxH[(3 * bi + qt) * 64 + d] = (__bf16)vv;
      }
    }
    __syncthreads();

    // ---- GEMM3 partial: attn_out += ctx_head [48,64] @ Wo[:, hd*64:+64].T ----
    for (int nc = 0; nc < 4; nc++) {
      __syncthreads();
      #pragma unroll
      for (int i = 0; i < 4; i++) {  // Wo chunk [128 rows][64 cols]
        int row = i * 32 + (tid >> 3), c = tid & 7;
        gl_lds16(Wo + (size_t)(nc * 128 + row) * 512 + hd * 64 + c * 8, &sW[row * 64 + c * 8]);
      }
      __syncthreads();
      #pragma unroll
      for (int kk = 0; kk < 2; kk++) {
        bf16x8 af[3];
        #pragma unroll
        for (int i = 0; i < 3; i++) af[i] = *(bf16x8*)&sCtxH[(i * 16 + lrow) * 64 + kk * 32 + quad * 8];
        #pragma unroll
        for (int j = 0; j < 2; j++) {
          bf16x8 bfr = *(bf16x8*)&sW[(wave * 32 + j * 16 + lrow) * 64 + kk * 32 + quad * 8];
          #pragma unroll
          for (int i = 0; i < 3; i++)
            oacc[i][nc * 2 + j] = __builtin_amdgcn_mfma_f32_16x16x32_bf16(af[i], bfr, oacc[i][nc * 2 + j], 0, 0, 0);
        }
      }
    }
    __syncthreads();  // before next head overwrites sA/sW/sQKV/sCtxH
  }

  // ---- epilogue: +bo, +gumbel, softmax over 3 tokens, store y0|y1|y2 ----
  for (int c = 0; c < 4; c++) {
    #pragma unroll
    for (int jj = 0; jj < 2; jj++) {
      int j = c * 2 + jj;
      int lcol = wave * 32 + jj * 16 + lrow;
      float bv = bo[c * 128 + lcol];
      #pragma unroll
      for (int i = 0; i < 3; i++)
        #pragma unroll
        for (int r = 0; r < 4; r++)
          sOut[(i * 16 + quad * 4 + r) * 128 + lcol] = oacc[i][j][r] + bv;
    }
    __syncthreads();
    for (int idx = tid; idx < 16 * 128; idx += 256) {
      int bb = idx >> 7, n = idx & 127;
      int gn = c * 128 + n;
      size_t b = (size_t)(bi0 + bb);
      const float* gg = gum + b * 3 * 512 + gn;
      float a0 = sOut[(3 * bb + 0) * 128 + n] + gg[0];
      float a1 = sOut[(3 * bb + 1) * 128 + n] + gg[512];
      float a2 = sOut[(3 * bb + 2) * 128 + n] + gg[1024];
      float mx = fmaxf(a0, fmaxf(a1, a2));
      float e0 = __expf(a0 - mx), e1 = __expf(a1 - mx), e2 = __expf(a2 - mx);
      float inv = 1.f / (e0 + e1 + e2);
      out[b * 512 + gn]                              = e0 * inv;
      out[(size_t)BATCH * 512 + b * 512 + gn]        = e1 * inv;
      out[(size_t)2 * BATCH * 512 + b * 512 + gn]    = e2 * inv;
    }
    __syncthreads();
  }
}

// ---------------- launch ----------------
extern "C" void kernel_launch(void* const* d_in, const int* in_sizes, int n_in,
                              void* d_out, int out_size, void* d_ws, size_t ws_size,
                              hipStream_t stream) {
  const float* x    = (const float*)d_in[0];
  const float* W_fc = (const float*)d_in[1];
  const float* b_fc = (const float*)d_in[2];
  const float* ln_g = (const float*)d_in[3];
  const float* ln_b = (const float*)d_in[4];
  const float* Wqkv = (const float*)d_in[5];
  const float* bqkv = (const float*)d_in[6];
  const float* Wo   = (const float*)d_in[7];
  const float* bo   = (const float*)d_in[8];
  const float* gum  = (const float*)d_in[9];
  float* out = (float*)d_out;

  // workspace layout (needs ~196 MB)
  char* ws = (char*)d_ws;
  __bf16* Wfc_bf  = (__bf16*)(ws);
  __bf16* Wqkv_bf = (__bf16*)(ws + 1572864);
  __bf16* Wo_bf   = (__bf16*)(ws + 3145728);
  __bf16* h       = (__bf16*)(ws + 3670016);  // [B,1536] bf16 = 201,326,592 B

  convert_kernel<<<768, 256, 0, stream>>>(W_fc, Wfc_bf, 196608);
  convert_kernel<<<768, 256, 0, stream>>>(Wqkv, Wqkv_bf, 196608);
  convert_kernel<<<256, 256, 0, stream>>>(Wo, Wo_bf, 65536);
  gemm1_kernel<<<dim3(12, 512), 256, 0, stream>>>(x, Wfc_bf, b_fc, h);
  ln_relu_kernel<<<16384, 256, 0, stream>>>(h, ln_g, ln_b);
  tail_kernel<<<4096, 256, 0, stream>>>(h, Wqkv_bf, bqkv, Wo_bf, bo, gum, out);
}